// Round 20
// baseline (977.568 us; speedup 1.0000x reference)
//
#include <hip/hip_runtime.h>
#include <hip/hip_bf16.h>

// ---------------------------------------------------------------------------
// WeightOnlyLinear: y = x @ dequant4(qweight, scales, qzeros) + bias
//   x (8192,4096) fp32 | scales (32,12288) | bias (12288) | qweight (512,12288)
//   qzeros (32,1536) | out (8192,12288) fp32
// R20: R18 structure (256x128 tile, 8 waves 4Mx2N, wave 64x64, 16x16x32
//   MFMA, 2 blocks/CU) with the LOW-DUP operand (A, 2x) in a 2-deep VGPR
//   ring via L2 and B in a ring-3 LDS (8KB slots, 24KB/block).
//   Per-block-phase LDS 88KB -> 40KB (measured binding pipe in R18);
//   VMEM 40KB ~ 714cy becomes the new bound.
//   Ledger (4 A-loads + 1 B-stage per phase, A first): entry vmcnt(1)
//   => LA(q), SB(q) complete; prologue LA0,SB0,SB1 -> vm1; tail vm1/vm0.
// ---------------------------------------------------------------------------

typedef __attribute__((ext_vector_type(8))) short short8;
typedef __attribute__((ext_vector_type(4))) float f32x4;

__device__ __forceinline__ short f2bf(float f) {
  unsigned u = __float_as_uint(f);
  u += 0x7fffu + ((u >> 16) & 1u);
  return (short)(u >> 16);
}

__device__ __forceinline__ void gload_lds16(const void* g, void* l) {
  __builtin_amdgcn_global_load_lds(
      (const __attribute__((address_space(1))) void*)g,
      (__attribute__((address_space(3))) void*)l,
      16, 0, 0);
}

__device__ __forceinline__ void bar() {
  asm volatile("" ::: "memory");
  __builtin_amdgcn_s_barrier();
  asm volatile("" ::: "memory");
}

// ---------------------------------------------------------------------------
// Pass 1 (R16 map): dequant qweight -> B' fragment-major (nb128, kt32) 8KB
// tiles. Chunk c (16B): col = nb*128 + (c>>6)*16 + (l&15); kw = kt*4+(l>>4).
// ---------------------------------------------------------------------------
__global__ __launch_bounds__(256) void dequant_tile_kernel(
    const int* __restrict__ qweight, const int* __restrict__ qzeros,
    const float* __restrict__ scales, short* __restrict__ Bt,
    int N, int K) {
  const int ktn = K >> 5;
  const int bx = blockIdx.x;
  const int nb = bx / ktn, kt = bx - nb * ktn;
  const int t = threadIdx.x;
  const int g = kt >> 2;  // GROUPSIZE=128 = 4 k32-tiles
  char* dst = (char*)Bt + (size_t)bx * 8192;
#pragma unroll
  for (int p = 0; p < 2; ++p) {
    const int c = p * 256 + t;
    const int l = c & 63;
    const int n = nb * 128 + (c >> 6) * 16 + (l & 15);
    const int kw = kt * 4 + (l >> 4);
    const float sc = scales[(size_t)g * N + n];
    const int zw = qzeros[(size_t)g * (N >> 3) + (n >> 3)];
    const float zs = -(float)(((zw >> ((n & 7) * 4)) & 15) + 1) * sc;
    const int w = qweight[(size_t)kw * N + n];
    short8 v;
#pragma unroll
    for (int e = 0; e < 8; ++e)
      v[e] = f2bf(fmaf((float)((w >> (4 * e)) & 15), sc, zs));
    *(short8*)(dst + c * 16) = v;
  }
}

// ---------------------------------------------------------------------------
// Pass 2 (R16 map): x fp32 -> A' fragment-major (mb256, kt32) 16KB tiles.
// ---------------------------------------------------------------------------
__global__ __launch_bounds__(256) void cvt_tile_kernel(
    const float* __restrict__ x, short* __restrict__ xb, int K) {
  const int ktn = K >> 5;
  const int bx = blockIdx.x;
  const int mb = bx / ktn, kt = bx - mb * ktn;
  char* dst = (char*)xb + (size_t)bx * 16384;
#pragma unroll
  for (int p = 0; p < 4; ++p) {
    const int c = p * 256 + threadIdx.x;
    const int l = c & 63;
    const int row = mb * 256 + (c >> 6) * 16 + (l & 15);
    const int k = kt * 32 + (l >> 4) * 8;
    const float* s = x + (size_t)row * K + k;
    float4 f0 = *(const float4*)s;
    float4 f1 = *(const float4*)(s + 4);
    short8 v;
    v[0] = f2bf(f0.x); v[1] = f2bf(f0.y); v[2] = f2bf(f0.z); v[3] = f2bf(f0.w);
    v[4] = f2bf(f1.x); v[5] = f2bf(f1.y); v[6] = f2bf(f1.z); v[7] = f2bf(f1.w);
    *(short8*)(dst + c * 16) = v;
  }
}

// ---------------------------------------------------------------------------
// Pass 3 (R20): 256x128 GEMM, 512 threads = 8 waves as 4M x 2N, wave 64x64.
// MFMA 16x16x32; acc f32x4[4][4]. LDS: ring-3 x 8192 (B only, 24KB).
// A: 2-deep VGPR ring aS[2][4], loaded 1 phase ahead via asm gloads.
// Phase q (slot q%3, aset q&1): {vm1 (ties aS[q&1]); bar; rdB(slot); LA(q+1)
//   [4]; SB(q+2) [1]; setprio 16 MFMA}. Tail: q=P-2 vm1 + LA only; P-1 vm0.
// ---------------------------------------------------------------------------
#define GBM 256
#define GBN 128

__global__ __launch_bounds__(512, 4) void gemm256_kernel(
    const short* __restrict__ At, const short* __restrict__ Bt,
    const float* __restrict__ bias, float* __restrict__ C,
    int M, int N, int K) {
  __shared__ __align__(16) char lds[3 * 8192];
  const int tid = threadIdx.x;
  const int nbx = N / GBN;
  const int nwg = gridDim.x;
  int bid = blockIdx.x;
  if ((nwg & 7) == 0) bid = (bid & 7) * (nwg >> 3) + (bid >> 3);  // T1
  const int mb = bid / nbx;
  const int nb = bid % nbx;
  const int bm = mb * GBM, bn = nb * GBN;

  const int wid = tid >> 6, lane = tid & 63;
  const int wr = wid >> 1, wc = wid & 1;  // 4M x 2N wave grid

  const int P = K >> 5;  // K-32 tiles; launcher guarantees (P-2)%6==0

  char* lb = &lds[0];

  // B frag j (cols wc*64 + j*16) at SL*8192 + (wc*4+j)*1024 + lane*16
  const char* bBase = lb + wc * 4096 + lane * 16;

  // B staging: 1 chunk/thread; linear dst
  const char* pBs = (const char*)Bt + (size_t)nb * P * 8192 + (size_t)tid * 16;
  char* dB = lb + tid * 16;

  // A register loads: wave's frag i of tile q at
  //   At + (mb*P + q)*16384 + (wr*4+i)*1024 + lane*16
  const char* pA = (const char*)At + (size_t)mb * P * 16384 + wr * 4096 +
                   (size_t)lane * 16;

  short8 aS[2][4];  // [set][i], statically indexed

#define STAGEB(TSL, BOFF) gload_lds16(pBs + (BOFF), dB + (TSL)*8192)

#define LOADA(SET, AOFF)                                             \
  do {                                                               \
    asm volatile("global_load_dwordx4 %0, %1, off"                   \
                 : "=v"(aS[SET][0]) : "v"(pA + (AOFF)));             \
    asm volatile("global_load_dwordx4 %0, %1, off"                   \
                 : "=v"(aS[SET][1]) : "v"(pA + (AOFF) + 1024));      \
    asm volatile("global_load_dwordx4 %0, %1, off"                   \
                 : "=v"(aS[SET][2]) : "v"(pA + (AOFF) + 2048));      \
    asm volatile("global_load_dwordx4 %0, %1, off"                   \
                 : "=v"(aS[SET][3]) : "v"(pA + (AOFF) + 3072));      \
  } while (0)

// wait vmcnt(N) and tie set SET's regs so MFMAs can't hoist above the wait
#define WAITA(NSTR, SET)                                                   \
  asm volatile("s_waitcnt vmcnt(" NSTR ")"                                 \
               : "+v"(aS[SET][0]), "+v"(aS[SET][1]), "+v"(aS[SET][2]),     \
                 "+v"(aS[SET][3])::"memory")

  short8 bR[4];

#define RDB(SL)                                                   \
  do {                                                            \
    _Pragma("unroll") for (int j = 0; j < 4; ++j) bR[j] =         \
        *(const short8*)(bBase + (SL)*8192 + j * 1024);           \
  } while (0)

  f32x4 acc[4][4] = {};

#define MFMA16(SET)                                                      \
  do {                                                                   \
    __builtin_amdgcn_s_setprio(1);                                       \
    _Pragma("unroll") for (int i = 0; i < 4; ++i)                        \
        _Pragma("unroll") for (int j = 0; j < 4; ++j) acc[i][j] =        \
            __builtin_amdgcn_mfma_f32_16x16x32_bf16(aS[SET][i], bR[j],   \
                                                    acc[i][j], 0, 0, 0); \
    __builtin_amdgcn_s_setprio(0);                                       \
  } while (0)

// body phase: slot SL = q%3, set = q&1; loads A(q+1) -> set^1, stages B(q+2)
#define PHASE(SL, SET, R)                                  \
  do {                                                     \
    WAITA("1", SET);                                       \
    bar();                                                 \
    RDB(SL);                                               \
    LOADA((SET) ^ 1, ((R) + 1) * 16384);                   \
    STAGEB(((SL) + 2) % 3, ((R) + 2) * 8192);              \
    MFMA16(SET);                                           \
  } while (0)

  // --- prologue: LA(0)->set0 [4], SB(0)->slot0 [1], SB(1)->slot1 [1] ---
  LOADA(0, 0);
  STAGEB(0, 0);
  STAGEB(1, 8192);

  // --- body: (P-2)/6 iterations of 6 phases (slots 0,1,2,0,1,2; sets
  //     0,1,0,1,0,1). Phase r of iteration: q = 6m + r. ---
  const int nIt = (P - 2) / 6;
  for (int it = 0; it < nIt; ++it) {
    PHASE(0, 0, 0);
    PHASE(1, 1, 1);
    PHASE(2, 0, 2);
    PHASE(0, 1, 3);
    PHASE(1, 0, 4);
    PHASE(2, 1, 5);
    pA += 6 * 16384;
    pBs += 6 * 8192;
  }
  // --- tail: q = P-2 (slot 0, set 0): vm1; LA(P-1)->set1; no stage.
  //           q = P-1 (slot 1, set 1): vm0. ---
  WAITA("1", 0);
  bar();
  RDB(0);
  LOADA(1, 1 * 16384);
  MFMA16(0);
  WAITA("0", 1);
  bar();
  RDB(1);
  MFMA16(1);

#undef PHASE
#undef MFMA16
#undef RDB
#undef WAITA
#undef LOADA
#undef STAGEB

  // --- epilogue: C = acc + bias. 16x16 C/D: col=lane&15, row=(lane>>4)*4+r
  const int crow0 = bm + wr * 64 + (lane >> 4) * 4;
  const int ccol0 = bn + wc * 64 + (lane & 15);
#pragma unroll
  for (int fj = 0; fj < 4; ++fj) {
    const float bv = bias[ccol0 + fj * 16];
#pragma unroll
    for (int fi = 0; fi < 4; ++fi) {
#pragma unroll
      for (int r = 0; r < 4; ++r) {
        C[(size_t)(crow0 + fi * 16 + r) * N + ccol0 + fj * 16] =
            acc[fi][fj][r] + bv;
      }
    }
  }
}

// ---------------------------------------------------------------------------
// Fallback prepasses (linear layouts) for non-divisible shapes.
// ---------------------------------------------------------------------------
__global__ __launch_bounds__(256) void dequant_kernel(
    const int* __restrict__ qweight, const int* __restrict__ qzeros,
    const float* __restrict__ scales, short* __restrict__ Wt,
    int in_f, int out_f) {
  __shared__ __align__(16) short T[64][72];
  const int n0 = blockIdx.x * 64;
  const int k0 = blockIdx.y * 64;
  const int t = threadIdx.x;
  const int nl = t & 63;
  const int kw = t >> 6;
  const int n = n0 + nl;
  const int g = k0 >> 7;
  const float sc = scales[(size_t)g * out_f + n];
  const int zpw = qzeros[(size_t)g * (out_f >> 3) + (n >> 3)];
  const float zp = (float)(((zpw >> ((n & 7) * 4)) & 15) + 1);
  const float zs = zp * sc;
#pragma unroll
  for (int rr = 0; rr < 2; ++rr) {
    const int kwi = kw + rr * 4;
    const int w = qweight[(size_t)((k0 >> 3) + kwi) * out_f + n];
    short8 v;
#pragma unroll
    for (int e = 0; e < 8; ++e) {
      float f = (float)((w >> (4 * e)) & 15) * sc - zs;
      v[e] = f2bf(f);
    }
    *(short8*)&T[nl][kwi * 8] = v;
  }
  __syncthreads();
#pragma unroll
  for (int rr = 0; rr < 2; ++rr) {
    const int c = rr * 256 + t;
    const int row = c >> 3, ch = c & 7;
    *(short8*)&Wt[(size_t)(n0 + row) * in_f + k0 + ch * 8] =
        *(const short8*)&T[row][ch * 8];
  }
}

__global__ __launch_bounds__(256) void cvt_kernel(
    const float* __restrict__ x, short* __restrict__ xb, long n8) {
  long i = (long)blockIdx.x * blockDim.x + threadIdx.x;
  if (i >= n8) return;
  const float* src = x + i * 8;
  float4 a = *(const float4*)src;
  float4 b = *(const float4*)(src + 4);
  short8 v;
  v[0] = f2bf(a.x); v[1] = f2bf(a.y); v[2] = f2bf(a.z); v[3] = f2bf(a.w);
  v[4] = f2bf(b.x); v[5] = f2bf(b.y); v[6] = f2bf(b.z); v[7] = f2bf(b.w);
  *(short8*)(xb + i * 8) = v;
}

// ---------------------------------------------------------------------------
// 128x128x64 GEMM (fallback for non-divisible shapes).
// ---------------------------------------------------------------------------
#define BM 128
#define BN 128
#define BK 64

template <bool A_BF16>
__global__ __launch_bounds__(256) void gemm_bias_kernel(
    const void* __restrict__ Av, const short* __restrict__ Bt,
    const float* __restrict__ bias, float* __restrict__ C,
    int M, int N, int K) {
  __shared__ __align__(16) short As[BM * BK];
  __shared__ __align__(16) short Bs[BN * BK];
  const int tid = threadIdx.x;
  const int bm = blockIdx.y * BM;
  const int bn = blockIdx.x * BN;
  const int wid = tid >> 6, lane = tid & 63;
  const int wr = wid >> 1, wc = wid & 1;
  const int lrow = lane & 15;
  const int lk = (lane >> 4) * 8;

  f32x4 acc[4][4] = {};

  for (int kt = 0; kt < K; kt += BK) {
    if constexpr (A_BF16) {
      const short* A = (const short*)Av;
#pragma unroll
      for (int r = 0; r < 4; ++r) {
        const int c = r * 256 + tid;
        const int row = c >> 3, ch = c & 7;
        gload_lds16(A + (size_t)(bm + row) * K + kt + ch * 8,
                    (char*)As + c * 16);
      }
    } else {
      const float* A = (const float*)Av;
#pragma unroll
      for (int r = 0; r < 4; ++r) {
        const int c = r * 256 + tid;
        const int row = c >> 3, ch = c & 7;
        const float* src = A + (size_t)(bm + row) * K + kt + ch * 8;
        float4 f0 = *(const float4*)src;
        float4 f1 = *(const float4*)(src + 4);
        short8 v;
        v[0] = f2bf(f0.x); v[1] = f2bf(f0.y); v[2] = f2bf(f0.z); v[3] = f2bf(f0.w);
        v[4] = f2bf(f1.x); v[5] = f2bf(f1.y); v[6] = f2bf(f1.z); v[7] = f2bf(f1.w);
        *(short8*)((char*)As + c * 16) = v;
      }
    }
#pragma unroll
    for (int r = 0; r < 4; ++r) {
      const int c = r * 256 + tid;
      const int row = c >> 3, ch = c & 7;
      gload_lds16(Bt + (size_t)(bn + row) * K + kt + ch * 8,
                  (char*)Bs + c * 16);
    }
    __syncthreads();
#pragma unroll
    for (int kk = 0; kk < 2; ++kk) {
      short8 af[4], bf[4];
#pragma unroll
      for (int i = 0; i < 4; ++i)
        af[i] = *(const short8*)&As[(wr * 64 + i * 16 + lrow) * BK + kk * 32 + lk];
#pragma unroll
      for (int j = 0; j < 4; ++j)
        bf[j] = *(const short8*)&Bs[(wc * 64 + j * 16 + lrow) * BK + kk * 32 + lk];
#pragma unroll
      for (int i = 0; i < 4; ++i)
#pragma unroll
        for (int j = 0; j < 4; ++j)
          acc[i][j] = __builtin_amdgcn_mfma_f32_16x16x32_bf16(
              af[i], bf[j], acc[i][j], 0, 0, 0);
    }
    __syncthreads();
  }

  const int crow0 = bm + wr * 64 + (lane >> 4) * 4;
  const int ccol0 = bn + wc * 64 + (lane & 15);
#pragma unroll
  for (int j = 0; j < 4; ++j) {
    const float bv = bias[ccol0 + j * 16];
#pragma unroll
    for (int i = 0; i < 4; ++i) {
#pragma unroll
      for (int r = 0; r < 4; ++r) {
        C[(size_t)(crow0 + i * 16 + r) * N + ccol0 + j * 16] = acc[i][j][r] + bv;
      }
    }
  }
}

// ---------------------------------------------------------------------------
// Last-resort fallback: naive fused dequant GEMM.
// ---------------------------------------------------------------------------
__global__ __launch_bounds__(256) void naive_kernel(
    const float* __restrict__ x, const float* __restrict__ scales,
    const float* __restrict__ bias, const int* __restrict__ qw,
    const int* __restrict__ qz, float* __restrict__ out,
    int M, int K, int N) {
  long idx = (long)blockIdx.x * blockDim.x + threadIdx.x;
  if (idx >= (long)M * N) return;
  const int n = (int)(idx % N);
  const int m = (int)(idx / N);
  float acc = 0.f;
  for (int g = 0; g < K / 128; ++g) {
    const float sc = scales[(size_t)g * N + n];
    const float zp =
        (float)(((qz[(size_t)g * (N >> 3) + (n >> 3)] >> ((n & 7) * 4)) & 15) + 1);
    const float zs = zp * sc;
    for (int kw = 0; kw < 16; ++kw) {
      const int w = qw[(size_t)(g * 16 + kw) * N + n];
      const float* xp = &x[(size_t)m * K + g * 128 + kw * 8];
#pragma unroll
      for (int e = 0; e < 8; ++e)
        acc += xp[e] * ((float)((w >> (4 * e)) & 15) * sc - zs);
    }
  }
  out[idx] = acc + bias[n];
}

// ---------------------------------------------------------------------------
extern "C" void kernel_launch(void* const* d_in, const int* in_sizes, int n_in,
                              void* d_out, int out_size, void* d_ws,
                              size_t ws_size, hipStream_t stream) {
  const float* x = (const float*)d_in[0];
  const float* scales = (const float*)d_in[1];
  const float* bias = (const float*)d_in[2];
  const int* qweight = (const int*)d_in[3];
  const int* qzeros = (const int*)d_in[4];
  float* out = (float*)d_out;

  const int out_f = in_sizes[2];            // 12288
  const int kwords = in_sizes[3] / out_f;   // 512
  const int in_f = kwords * 8;              // 4096
  const int tokens = in_sizes[0] / in_f;    // 8192
  const int M = tokens, K = in_f, N = out_f;

  const size_t wt_bytes = (size_t)K * N * sizeof(short);
  const size_t xb_bytes = (size_t)M * K * sizeof(short);

  const bool div128 = (M % BM == 0) && (N % BN == 0) && (K % BK == 0) &&
                      (K % 128 == 0) && (N % 64 == 0);
  const bool divR20 = (M % GBM == 0) && (N % GBN == 0) && (K % 256 == 0) &&
                      (((K >> 5) - 2) % 6 == 0);

  if (divR20 && ws_size >= wt_bytes + xb_bytes) {
    // R20 pre-tiled path
    short* Btile = (short*)d_ws;                        // B' fragment tiles
    short* Atile = (short*)((char*)d_ws + wt_bytes);    // A' fragment tiles
    const int ktn = K >> 5;
    dequant_tile_kernel<<<(N / 128) * ktn, 256, 0, stream>>>(
        qweight, qzeros, scales, Btile, N, K);
    cvt_tile_kernel<<<(M / 256) * ktn, 256, 0, stream>>>(x, Atile, K);
    gemm256_kernel<<<(M / GBM) * (N / GBN), 512, 0, stream>>>(
        Atile, Btile, bias, out, M, N, K);
  } else if (div128 && ws_size >= wt_bytes + xb_bytes) {
    short* Wt = (short*)d_ws;
    short* xb = (short*)((char*)d_ws + wt_bytes);
    dequant_kernel<<<dim3(N / 64, K / 64), 256, 0, stream>>>(
        qweight, qzeros, scales, Wt, K, N);
    const long n8 = (long)M * K / 8;
    cvt_kernel<<<(int)((n8 + 255) / 256), 256, 0, stream>>>(x, xb, n8);
    gemm_bias_kernel<true><<<dim3(N / BN, M / BM), 256, 0, stream>>>(
        xb, Wt, bias, out, M, N, K);
  } else if (div128 && ws_size >= wt_bytes) {
    short* Wt = (short*)d_ws;
    dequant_kernel<<<dim3(N / 64, K / 64), 256, 0, stream>>>(
        qweight, qzeros, scales, Wt, K, N);
    gemm_bias_kernel<false><<<dim3(N / BN, M / BM), 256, 0, stream>>>(
        x, Wt, bias, out, M, N, K);
  } else {
    const long total = (long)M * N;
    naive_kernel<<<(int)((total + 255) / 256), 256, 0, stream>>>(
        x, scales, bias, qweight, qzeros, out, M, K, N);
  }
}

// Round 21
// 745.845 us; speedup vs baseline: 1.3107x; 1.3107x over previous
//
#include <hip/hip_runtime.h>
#include <hip/hip_bf16.h>

// ---------------------------------------------------------------------------
// WeightOnlyLinear: y = x @ dequant4(qweight, scales, qzeros) + bias
//   x (8192,4096) fp32 | scales (32,12288) | bias (12288) | qweight (512,12288)
//   qzeros (32,1536) | out (8192,12288) fp32
// FINAL (= R18, session best: 751 us total, GEMM 677 us ~ 1220 TF):
//   - prepasses write A'/B' in fragment-major tile layout (staging and
//     ds_reads both linear, 0 bank conflicts, no address math)
//   - GEMM: 256x128 tile, 8 waves as 4M x 2N (wave 64x64, minimal read-dup
//     2xA/4xB = 64KB frag reads + 24KB DMA per block-phase), 16x16x32 MFMA,
//     ring-3 x 24KB LDS, launch_bounds(512,4) -> 2 co-resident blocks/CU
//     (one block's MFMAs fill the other's barrier/vmcnt gaps),
//     counted vmcnt(3) + 1 barrier per K-32 phase, T1 XCD swizzle, setprio.
//   Measured: LDS pipe saturated (88KB/phase @ ~83B/cy) -> structural
//   roofline for this decomposition; both operand-to-register bypasses
//   (R19/R20) measured negative.
// ---------------------------------------------------------------------------

typedef __attribute__((ext_vector_type(8))) short short8;
typedef __attribute__((ext_vector_type(4))) float f32x4;

__device__ __forceinline__ short f2bf(float f) {
  unsigned u = __float_as_uint(f);
  u += 0x7fffu + ((u >> 16) & 1u);
  return (short)(u >> 16);
}

__device__ __forceinline__ void gload_lds16(const void* g, void* l) {
  __builtin_amdgcn_global_load_lds(
      (const __attribute__((address_space(1))) void*)g,
      (__attribute__((address_space(3))) void*)l,
      16, 0, 0);
}

__device__ __forceinline__ void bar() {
  asm volatile("" ::: "memory");
  __builtin_amdgcn_s_barrier();
  asm volatile("" ::: "memory");
}
__device__ __forceinline__ void wait_vm3() {
  asm volatile("s_waitcnt vmcnt(3)" ::: "memory");
}
__device__ __forceinline__ void wait_vm0() {
  asm volatile("s_waitcnt vmcnt(0)" ::: "memory");
}

// ---------------------------------------------------------------------------
// Pass 1: dequant qweight -> B' fragment-major (nb128, kt32) 8KB tiles.
// Chunk c (16B): col = nb*128 + (c>>6)*16 + (l&15); kw = kt*4 + (l>>4).
// One qweight word == one chunk. grid = (N/128)*(K/32), 2 chunks/thr.
// ---------------------------------------------------------------------------
__global__ __launch_bounds__(256) void dequant_tile_kernel(
    const int* __restrict__ qweight, const int* __restrict__ qzeros,
    const float* __restrict__ scales, short* __restrict__ Bt,
    int N, int K) {
  const int ktn = K >> 5;
  const int bx = blockIdx.x;
  const int nb = bx / ktn, kt = bx - nb * ktn;
  const int t = threadIdx.x;
  const int g = kt >> 2;  // GROUPSIZE=128 = 4 k32-tiles
  char* dst = (char*)Bt + (size_t)bx * 8192;
#pragma unroll
  for (int p = 0; p < 2; ++p) {
    const int c = p * 256 + t;
    const int l = c & 63;
    const int n = nb * 128 + (c >> 6) * 16 + (l & 15);
    const int kw = kt * 4 + (l >> 4);
    const float sc = scales[(size_t)g * N + n];
    const int zw = qzeros[(size_t)g * (N >> 3) + (n >> 3)];
    const float zs = -(float)(((zw >> ((n & 7) * 4)) & 15) + 1) * sc;
    const int w = qweight[(size_t)kw * N + n];
    short8 v;
#pragma unroll
    for (int e = 0; e < 8; ++e)
      v[e] = f2bf(fmaf((float)((w >> (4 * e)) & 15), sc, zs));
    *(short8*)(dst + c * 16) = v;
  }
}

// ---------------------------------------------------------------------------
// Pass 2: x fp32 -> A' fragment-major (mb256, kt32) 16KB tiles.
// Chunk c: row = mb*256 + (c>>6)*16 + (l&15); k = kt*32 + (l>>4)*8.
// grid = (M/256)*(K/32), 4 chunks/thr.
// ---------------------------------------------------------------------------
__global__ __launch_bounds__(256) void cvt_tile_kernel(
    const float* __restrict__ x, short* __restrict__ xb, int K) {
  const int ktn = K >> 5;
  const int bx = blockIdx.x;
  const int mb = bx / ktn, kt = bx - mb * ktn;
  char* dst = (char*)xb + (size_t)bx * 16384;
#pragma unroll
  for (int p = 0; p < 4; ++p) {
    const int c = p * 256 + threadIdx.x;
    const int l = c & 63;
    const int row = mb * 256 + (c >> 6) * 16 + (l & 15);
    const int k = kt * 32 + (l >> 4) * 8;
    const float* s = x + (size_t)row * K + k;
    float4 f0 = *(const float4*)s;
    float4 f1 = *(const float4*)(s + 4);
    short8 v;
    v[0] = f2bf(f0.x); v[1] = f2bf(f0.y); v[2] = f2bf(f0.z); v[3] = f2bf(f0.w);
    v[4] = f2bf(f1.x); v[5] = f2bf(f1.y); v[6] = f2bf(f1.z); v[7] = f2bf(f1.w);
    *(short8*)(dst + c * 16) = v;
  }
}

// ---------------------------------------------------------------------------
// Pass 3: 256x128 GEMM, 512 threads = 8 waves as 4M x 2N, wave 64x64.
// MFMA 16x16x32; acc f32x4[4][4]. LDS: ring-3 x 24576 (A 16KB @0, B 8KB
// @16384), fragment-major. Phase q (slot q%3): {vm3; bar; 8 frag reads;
// stage tile q+2 -> slot (q+2)%3 [3 gloads]; setprio 16 MFMA}.
// Tail peel: vm3 / vm0.
// ---------------------------------------------------------------------------
#define GBM 256
#define GBN 128

__global__ __launch_bounds__(512, 4) void gemm256_kernel(
    const short* __restrict__ At, const short* __restrict__ Bt,
    const float* __restrict__ bias, float* __restrict__ C,
    int M, int N, int K) {
  __shared__ __align__(16) char lds[3 * 24576];
  const int tid = threadIdx.x;
  const int nbx = N / GBN;
  const int nwg = gridDim.x;
  int bid = blockIdx.x;
  if ((nwg & 7) == 0) bid = (bid & 7) * (nwg >> 3) + (bid >> 3);  // T1
  const int mb = bid / nbx;
  const int nb = bid % nbx;
  const int bm = mb * GBM, bn = nb * GBN;

  const int wid = tid >> 6, lane = tid & 63;
  const int wr = wid >> 1, wc = wid & 1;  // 4M x 2N wave grid

  const int P = K >> 5;  // K-32 tiles; launcher guarantees (P-2)%3==0

  char* lb = &lds[0];

  // frag read bases: A frag i (rows wr*64 + i*16) at
  //   SL*24576 + (wr*4+i)*1024 + lane*16;
  // B frag j (cols wc*64 + j*16) at 16384 + SL*24576 + (wc*4+j)*1024 + lane*16.
  const char* aBase = lb + wr * 4096 + lane * 16;
  const char* bBase = lb + 16384 + wc * 4096 + lane * 16;

  // staging: A chunks {tid, tid+512}, B chunk {tid}; linear dst
  const char* pA = (const char*)At + (size_t)mb * P * 16384 + (size_t)tid * 16;
  const char* pB = (const char*)Bt + (size_t)nb * P * 8192 + (size_t)tid * 16;
  char* dA = lb + tid * 16;
  char* dB = lb + 16384 + tid * 16;

#define STAGE(TSL, AOFF, BOFF)                                \
  do {                                                        \
    gload_lds16(pA + (AOFF), dA + (TSL)*24576);               \
    gload_lds16(pA + (AOFF) + 8192, dA + (TSL)*24576 + 8192); \
    gload_lds16(pB + (BOFF), dB + (TSL)*24576);               \
  } while (0)

  short8 aR[4], bR[4];

#define RD(SL)                                                        \
  do {                                                                \
    _Pragma("unroll") for (int i = 0; i < 4; ++i) aR[i] =             \
        *(const short8*)(aBase + (SL)*24576 + i * 1024);              \
    _Pragma("unroll") for (int j = 0; j < 4; ++j) bR[j] =             \
        *(const short8*)(bBase + (SL)*24576 + j * 1024);              \
  } while (0)

  f32x4 acc[4][4] = {};

#define MFMA16()                                                         \
  do {                                                                   \
    __builtin_amdgcn_s_setprio(1);                                       \
    _Pragma("unroll") for (int i = 0; i < 4; ++i)                        \
        _Pragma("unroll") for (int j = 0; j < 4; ++j) acc[i][j] =        \
            __builtin_amdgcn_mfma_f32_16x16x32_bf16(aR[i], bR[j],        \
                                                    acc[i][j], 0, 0, 0); \
    __builtin_amdgcn_s_setprio(0);                                       \
  } while (0)

  // prologue: tile0 -> slot0, tile1 -> slot1 (6 gloads)
  STAGE(0, 0, 0);
  STAGE(1, 16384, 8192);

  // body: (P-2)/3 iterations x 3 phases; phase q stages tile q+2.
  const int nIt = (P - 2) / 3;
  for (int it = 0; it < nIt; ++it) {
    wait_vm3(); bar();
    RD(0); STAGE(2, 2 * 16384, 2 * 8192); MFMA16();
    wait_vm3(); bar();
    RD(1); STAGE(0, 3 * 16384, 3 * 8192); MFMA16();
    wait_vm3(); bar();
    RD(2); STAGE(1, 4 * 16384, 4 * 8192); MFMA16();
    pA += 3 * 16384;
    pB += 3 * 8192;
  }
  // peel: q = P-2 (slot 0), q = P-1 (slot 1)
  wait_vm3(); bar();
  RD(0); MFMA16();
  wait_vm0(); bar();
  RD(1); MFMA16();

#undef MFMA16
#undef RD
#undef STAGE

  // epilogue: C = acc + bias. 16x16 C/D: col=lane&15, row=(lane>>4)*4+r
  const int crow0 = bm + wr * 64 + (lane >> 4) * 4;
  const int ccol0 = bn + wc * 64 + (lane & 15);
#pragma unroll
  for (int fj = 0; fj < 4; ++fj) {
    const float bv = bias[ccol0 + fj * 16];
#pragma unroll
    for (int fi = 0; fi < 4; ++fi) {
#pragma unroll
      for (int r = 0; r < 4; ++r) {
        C[(size_t)(crow0 + fi * 16 + r) * N + ccol0 + fj * 16] =
            acc[fi][fj][r] + bv;
      }
    }
  }
}

// ---------------------------------------------------------------------------
// Fallback prepasses (linear layouts) for non-divisible shapes.
// ---------------------------------------------------------------------------
__global__ __launch_bounds__(256) void dequant_kernel(
    const int* __restrict__ qweight, const int* __restrict__ qzeros,
    const float* __restrict__ scales, short* __restrict__ Wt,
    int in_f, int out_f) {
  __shared__ __align__(16) short T[64][72];
  const int n0 = blockIdx.x * 64;
  const int k0 = blockIdx.y * 64;
  const int t = threadIdx.x;
  const int nl = t & 63;
  const int kw = t >> 6;
  const int n = n0 + nl;
  const int g = k0 >> 7;
  const float sc = scales[(size_t)g * out_f + n];
  const int zpw = qzeros[(size_t)g * (out_f >> 3) + (n >> 3)];
  const float zp = (float)(((zpw >> ((n & 7) * 4)) & 15) + 1);
  const float zs = zp * sc;
#pragma unroll
  for (int rr = 0; rr < 2; ++rr) {
    const int kwi = kw + rr * 4;
    const int w = qweight[(size_t)((k0 >> 3) + kwi) * out_f + n];
    short8 v;
#pragma unroll
    for (int e = 0; e < 8; ++e) {
      float f = (float)((w >> (4 * e)) & 15) * sc - zs;
      v[e] = f2bf(f);
    }
    *(short8*)&T[nl][kwi * 8] = v;
  }
  __syncthreads();
#pragma unroll
  for (int rr = 0; rr < 2; ++rr) {
    const int c = rr * 256 + t;
    const int row = c >> 3, ch = c & 7;
    *(short8*)&Wt[(size_t)(n0 + row) * in_f + k0 + ch * 8] =
        *(const short8*)&T[row][ch * 8];
  }
}

__global__ __launch_bounds__(256) void cvt_kernel(
    const float* __restrict__ x, short* __restrict__ xb, long n8) {
  long i = (long)blockIdx.x * blockDim.x + threadIdx.x;
  if (i >= n8) return;
  const float* src = x + i * 8;
  float4 a = *(const float4*)src;
  float4 b = *(const float4*)(src + 4);
  short8 v;
  v[0] = f2bf(a.x); v[1] = f2bf(a.y); v[2] = f2bf(a.z); v[3] = f2bf(a.w);
  v[4] = f2bf(b.x); v[5] = f2bf(b.y); v[6] = f2bf(b.z); v[7] = f2bf(b.w);
  *(short8*)(xb + i * 8) = v;
}

// ---------------------------------------------------------------------------
// 128x128x64 GEMM (fallback for non-divisible shapes).
// ---------------------------------------------------------------------------
#define BM 128
#define BN 128
#define BK 64

template <bool A_BF16>
__global__ __launch_bounds__(256) void gemm_bias_kernel(
    const void* __restrict__ Av, const short* __restrict__ Bt,
    const float* __restrict__ bias, float* __restrict__ C,
    int M, int N, int K) {
  __shared__ __align__(16) short As[BM * BK];
  __shared__ __align__(16) short Bs[BN * BK];
  const int tid = threadIdx.x;
  const int bm = blockIdx.y * BM;
  const int bn = blockIdx.x * BN;
  const int wid = tid >> 6, lane = tid & 63;
  const int wr = wid >> 1, wc = wid & 1;
  const int lrow = lane & 15;
  const int lk = (lane >> 4) * 8;

  f32x4 acc[4][4] = {};

  for (int kt = 0; kt < K; kt += BK) {
    if constexpr (A_BF16) {
      const short* A = (const short*)Av;
#pragma unroll
      for (int r = 0; r < 4; ++r) {
        const int c = r * 256 + tid;
        const int row = c >> 3, ch = c & 7;
        gload_lds16(A + (size_t)(bm + row) * K + kt + ch * 8,
                    (char*)As + c * 16);
      }
    } else {
      const float* A = (const float*)Av;
#pragma unroll
      for (int r = 0; r < 4; ++r) {
        const int c = r * 256 + tid;
        const int row = c >> 3, ch = c & 7;
        const float* src = A + (size_t)(bm + row) * K + kt + ch * 8;
        float4 f0 = *(const float4*)src;
        float4 f1 = *(const float4*)(src + 4);
        short8 v;
        v[0] = f2bf(f0.x); v[1] = f2bf(f0.y); v[2] = f2bf(f0.z); v[3] = f2bf(f0.w);
        v[4] = f2bf(f1.x); v[5] = f2bf(f1.y); v[6] = f2bf(f1.z); v[7] = f2bf(f1.w);
        *(short8*)((char*)As + c * 16) = v;
      }
    }
#pragma unroll
    for (int r = 0; r < 4; ++r) {
      const int c = r * 256 + tid;
      const int row = c >> 3, ch = c & 7;
      gload_lds16(Bt + (size_t)(bn + row) * K + kt + ch * 8,
                  (char*)Bs + c * 16);
    }
    __syncthreads();
#pragma unroll
    for (int kk = 0; kk < 2; ++kk) {
      short8 af[4], bf[4];
#pragma unroll
      for (int i = 0; i < 4; ++i)
        af[i] = *(const short8*)&As[(wr * 64 + i * 16 + lrow) * BK + kk * 32 + lk];
#pragma unroll
      for (int j = 0; j < 4; ++j)
        bf[j] = *(const short8*)&Bs[(wc * 64 + j * 16 + lrow) * BK + kk * 32 + lk];
#pragma unroll
      for (int i = 0; i < 4; ++i)
#pragma unroll
        for (int j = 0; j < 4; ++j)
          acc[i][j] = __builtin_amdgcn_mfma_f32_16x16x32_bf16(
              af[i], bf[j], acc[i][j], 0, 0, 0);
    }
    __syncthreads();
  }

  const int crow0 = bm + wr * 64 + (lane >> 4) * 4;
  const int ccol0 = bn + wc * 64 + (lane & 15);
#pragma unroll
  for (int j = 0; j < 4; ++j) {
    const float bv = bias[ccol0 + j * 16];
#pragma unroll
    for (int i = 0; i < 4; ++i) {
#pragma unroll
      for (int r = 0; r < 4; ++r) {
        C[(size_t)(crow0 + i * 16 + r) * N + ccol0 + j * 16] = acc[i][j][r] + bv;
      }
    }
  }
}

// ---------------------------------------------------------------------------
// Last-resort fallback: naive fused dequant GEMM.
// ---------------------------------------------------------------------------
__global__ __launch_bounds__(256) void naive_kernel(
    const float* __restrict__ x, const float* __restrict__ scales,
    const float* __restrict__ bias, const int* __restrict__ qw,
    const int* __restrict__ qz, float* __restrict__ out,
    int M, int K, int N) {
  long idx = (long)blockIdx.x * blockDim.x + threadIdx.x;
  if (idx >= (long)M * N) return;
  const int n = (int)(idx % N);
  const int m = (int)(idx / N);
  float acc = 0.f;
  for (int g = 0; g < K / 128; ++g) {
    const float sc = scales[(size_t)g * N + n];
    const float zp =
        (float)(((qz[(size_t)g * (N >> 3) + (n >> 3)] >> ((n & 7) * 4)) & 15) + 1);
    const float zs = zp * sc;
    for (int kw = 0; kw < 16; ++kw) {
      const int w = qw[(size_t)(g * 16 + kw) * N + n];
      const float* xp = &x[(size_t)m * K + g * 128 + kw * 8];
#pragma unroll
      for (int e = 0; e < 8; ++e)
        acc += xp[e] * ((float)((w >> (4 * e)) & 15) * sc - zs);
    }
  }
  out[idx] = acc + bias[n];
}

// ---------------------------------------------------------------------------
extern "C" void kernel_launch(void* const* d_in, const int* in_sizes, int n_in,
                              void* d_out, int out_size, void* d_ws,
                              size_t ws_size, hipStream_t stream) {
  const float* x = (const float*)d_in[0];
  const float* scales = (const float*)d_in[1];
  const float* bias = (const float*)d_in[2];
  const int* qweight = (const int*)d_in[3];
  const int* qzeros = (const int*)d_in[4];
  float* out = (float*)d_out;

  const int out_f = in_sizes[2];            // 12288
  const int kwords = in_sizes[3] / out_f;   // 512
  const int in_f = kwords * 8;              // 4096
  const int tokens = in_sizes[0] / in_f;    // 8192
  const int M = tokens, K = in_f, N = out_f;

  const size_t wt_bytes = (size_t)K * N * sizeof(short);
  const size_t xb_bytes = (size_t)M * K * sizeof(short);

  const bool div128 = (M % BM == 0) && (N % BN == 0) && (K % BK == 0) &&
                      (K % 128 == 0) && (N % 64 == 0);
  const bool divFast = (M % GBM == 0) && (N % GBN == 0) && (K % 256 == 0) &&
                       (((K >> 5) - 2) % 3 == 0);

  if (divFast && ws_size >= wt_bytes + xb_bytes) {
    // fast pre-tiled path (R18)
    short* Btile = (short*)d_ws;                        // B' fragment tiles
    short* Atile = (short*)((char*)d_ws + wt_bytes);    // A' fragment tiles
    const int ktn = K >> 5;
    dequant_tile_kernel<<<(N / 128) * ktn, 256, 0, stream>>>(
        qweight, qzeros, scales, Btile, N, K);
    cvt_tile_kernel<<<(M / 256) * ktn, 256, 0, stream>>>(x, Atile, K);
    gemm256_kernel<<<(M / GBM) * (N / GBN), 512, 0, stream>>>(
        Atile, Btile, bias, out, M, N, K);
  } else if (div128 && ws_size >= wt_bytes + xb_bytes) {
    short* Wt = (short*)d_ws;
    short* xb = (short*)((char*)d_ws + wt_bytes);
    dequant_kernel<<<dim3(N / 64, K / 64), 256, 0, stream>>>(
        qweight, qzeros, scales, Wt, K, N);
    const long n8 = (long)M * K / 8;
    cvt_kernel<<<(int)((n8 + 255) / 256), 256, 0, stream>>>(x, xb, n8);
    gemm_bias_kernel<true><<<dim3(N / BN, M / BM), 256, 0, stream>>>(
        xb, Wt, bias, out, M, N, K);
  } else if (div128 && ws_size >= wt_bytes) {
    short* Wt = (short*)d_ws;
    dequant_kernel<<<dim3(N / 64, K / 64), 256, 0, stream>>>(
        qweight, qzeros, scales, Wt, K, N);
    gemm_bias_kernel<false><<<dim3(N / BN, M / BM), 256, 0, stream>>>(
        x, Wt, bias, out, M, N, K);
  } else {
    const long total = (long)M * N;
    naive_kernel<<<(int)((total + 255) / 256), 256, 0, stream>>>(
        x, scales, bias, qweight, qzeros, out, M, K, N);
  }
}